// Round 3
// baseline (69.830 us; speedup 1.0000x reference)
//
#include <hip/hip_runtime.h>
#include <math.h>
#include <float.h>

#define NB 50      // NB_STEPS
#define NS 52      // 51 quadrature nodes padded to 52 (index 51: zero weight)
#define H  128     // hidden dim
#define SPT 13     // nodes per thread (4 threads/output * 13 = 52)

// Piecewise-linear reformulation of the integrand (see round-2 notes):
//   f(X) = A(X)*X + B(X) + b2 with 128 sorted breakpoints; per-node evaluation
//   is a branchless lower-bound search + one fma.
// Round-3 changes:
//   * first 3 search steps (st=128/64/32) read only {t[31],t[63],t[95],t[127]}
//     or known-FLT_MAX pad -> hoisted to registers (saves 3 dependent ~120cyc
//     LDS round-trips per node batch)
//   * (pA,pB) and (ccs,ccw) packed as float2 -> single ds_read_b64 each
//   * FIXED missing __syncthreads between prefix-fixup writes and eval reads
//     (round-2 raced; won only because the 8-step search delayed the reads)
__global__ __launch_bounds__(256) void umnn_pw(
    const float* __restrict__ x,
    const float* __restrict__ W1,
    const float* __restrict__ b1,
    const float* __restrict__ W2,
    const float* __restrict__ b2,
    float* __restrict__ out,
    int N)
{
    __shared__ __align__(16) float s_tmp[H];   // unsorted breakpoints (rank phase)
    __shared__ float  s_t[2 * H];              // sorted breakpoints + FLT_MAX pad
    __shared__ float  s_dA[H], s_dB[H];        // sorted deltas
    __shared__ float2 s_pAB[H + 1];            // prefix (A,B), k in [0,128]
    __shared__ float2 s_cc[NS];                // (node position, weight)
    __shared__ float  s_red[8];                // wave partials

    const int tid = threadIdx.x;

    // ---- Phase 1: per-unit quantities (waves 0-1) | CC weights (wave 2) ----
    float t = 0.0f, dA = 0.0f, dB = 0.0f;
    if (tid < H) {
        const float w1 = W1[tid];
        const float bb = b1[tid];
        const float w2 = W2[tid];
        const bool zero = (w1 == 0.0f);
        t = zero ? FLT_MAX : (-bb / w1);
        const float sgn = (w1 > 0.0f) ? 1.0f : -1.0f;
        dA = zero ? 0.0f : sgn * w2 * w1;
        dB = zero ? 0.0f : sgn * w2 * bb;
        float baseA = (w1 < 0.0f) ? w2 * w1 : 0.0f;   // active set at X=-inf
        float baseB = (w1 < 0.0f) ? w2 * bb : (zero ? w2 * fmaxf(bb, 0.0f) : 0.0f);
        s_tmp[tid] = t;
        s_t[H + tid] = FLT_MAX;                // sentinel pad for the search
#pragma unroll
        for (int off = 1; off < 64; off <<= 1) {
            baseA += __shfl_xor(baseA, off);
            baseB += __shfl_xor(baseB, off);
        }
        if ((tid & 63) == 0) {
            s_red[(tid >> 6) * 2 + 0] = baseA;
            s_red[(tid >> 6) * 2 + 1] = baseB;
        }
    } else if (tid < H + NS) {
        const int s = tid - H;
        if (s <= NB) {
            const float ccs = __cosf((float)s * ((float)M_PI / (float)NB));
            float sum = 0.0f;
            for (int kk = 0; kk <= NB; kk += 2) {   // odd k: W[k]=0
                float L;
                if (s == 0)       L = 0.5f;
                else if (s == NB) L = 0.5f;         // 0.5*cos(k*pi), k even
                else              L = __cosf((float)(kk * s) * ((float)M_PI / (float)NB));
                const float Wk = (kk == 0) ? 1.0f : 2.0f / (1.0f - (float)(kk * kk));
                sum += L * Wk;
            }
            s_cc[s] = make_float2(ccs, sum * (2.0f / (float)NB));
        } else {
            s_cc[s] = make_float2(0.0f, 0.0f);   // pad node: finite pos, zero wt
        }
    }
    __syncthreads();

    // ---- Phase 2: rank (broadcast LDS reads) and scatter ----
    if (tid < H) {
        const float4* t4 = (const float4*)s_tmp;
        int rank = 0;
#pragma unroll 8
        for (int j4 = 0; j4 < H / 4; ++j4) {
            const float4 v = t4[j4];             // wave-uniform -> broadcast
            const int jb = 4 * j4;
            rank += (v.x < t) || (v.x == t && (jb + 0) < tid);
            rank += (v.y < t) || (v.y == t && (jb + 1) < tid);
            rank += (v.z < t) || (v.z == t && (jb + 2) < tid);
            rank += (v.w < t) || (v.w == t && (jb + 3) < tid);
        }
        s_t[rank]  = t;                          // index tie-break => permutation
        s_dA[rank] = dA;
        s_dB[rank] = dB;
    }
    __syncthreads();

    // ---- Phase 3a: inclusive shuffle-scan of sorted deltas ----
    float sa = 0.0f, sb = 0.0f;
    if (tid < H) {
        sa = s_dA[tid];
        sb = s_dB[tid];
        const int lane = tid & 63;
#pragma unroll
        for (int off = 1; off < 64; off <<= 1) {
            const float ta = __shfl_up(sa, off);
            const float tb = __shfl_up(sb, off);
            if (lane >= off) { sa += ta; sb += tb; }
        }
        if (lane == 63) {
            s_red[4 + (tid >> 6) * 2] = sa;
            s_red[5 + (tid >> 6) * 2] = sb;
        }
    }
    __syncthreads();
    // ---- Phase 3b: cross-wave fixup -> prefix arrays ----
    if (tid < H) {
        const float A0 = s_red[0] + s_red[2];
        const float B0 = s_red[1] + s_red[3];
        const float addA = A0 + ((tid >= 64) ? s_red[4] : 0.0f);
        const float addB = B0 + ((tid >= 64) ? s_red[5] : 0.0f);
        s_pAB[tid + 1] = make_float2(sa + addA, sb + addB);
        if (tid == 0) s_pAB[0] = make_float2(A0, B0);
    }
    __syncthreads();   // round-2 was missing this barrier (race on s_pA/s_pB)

    // ---- Phase 4: evaluate quadrature nodes ----
    const int g = blockIdx.x * blockDim.x + tid;
    const int n = g >> 2;        // output point
    const int chunk = g & 3;     // which 13-node slice
    if (n >= N) return;

    const float xf  = x[n];
    const float b2v = b2[0];
    const int   s0  = chunk * SPT;

    // register head of the search tree (wave-uniform broadcast reads)
    const float tq0 = s_t[31], tq1 = s_t[63], tq2 = s_t[95], tq3 = s_t[127];

    float Xi[SPT], ccw[SPT];
    int   k[SPT];
#pragma unroll
    for (int i = 0; i < SPT; ++i) {
        const float2 cc = s_cc[s0 + i];
        Xi[i]  = xf * (cc.x + 1.0f) * 0.5f;
        ccw[i] = cc.y;
    }
    // Lower-bound (count of t < Xi). Steps 128/64/32 from registers:
    //   st=128 -> t[127]=tq3; st=64 -> idx k+63 in {63, 191(pad)} -> tq1 or MAX;
    //   st=32  -> idx k+31 in {31, 95, 159(pad)} -> tq0 / tq2 / MAX.
#pragma unroll
    for (int i = 0; i < SPT; ++i) k[i] = (tq3 < Xi[i]) ? 128 : 0;
#pragma unroll
    for (int i = 0; i < SPT; ++i) {
        const float v = (k[i] & 128) ? FLT_MAX : tq1;
        k[i] += (v < Xi[i]) ? 64 : 0;
    }
#pragma unroll
    for (int i = 0; i < SPT; ++i) {
        const float v = (k[i] == 0) ? tq0 : ((k[i] == 64) ? tq2 : FLT_MAX);
        k[i] += (v < Xi[i]) ? 32 : 0;
    }
    // Remaining 5 steps via LDS; step-outer / node-inner keeps 13 independent
    // reads in flight per step to hide the dependent-chain latency.
#pragma unroll
    for (int st = 16; st >= 1; st >>= 1) {
#pragma unroll
        for (int i = 0; i < SPT; ++i) {
            k[i] += (s_t[k[i] + st - 1] < Xi[i]) ? st : 0;
        }
    }
    float z = 0.0f;
#pragma unroll
    for (int i = 0; i < SPT; ++i) {
        const float2 AB = s_pAB[k[i]];           // one ds_read_b64
        const float f = fmaf(AB.x, Xi[i], AB.y) + b2v;
        const float e = (f > 0.0f) ? f : (__expf(f) - 1.0f);   // elu
        z = fmaf(e + 1.0f, ccw[i], z);
    }

    z += __shfl_xor(z, 1);
    z += __shfl_xor(z, 2);
    if (chunk == 0) out[n] = z * xf * 0.5f;
}

extern "C" void kernel_launch(void* const* d_in, const int* in_sizes, int n_in,
                              void* d_out, int out_size, void* d_ws, size_t ws_size,
                              hipStream_t stream) {
    const float* x  = (const float*)d_in[0];
    const float* W1 = (const float*)d_in[1];
    const float* b1 = (const float*)d_in[2];
    const float* W2 = (const float*)d_in[3];
    const float* b2 = (const float*)d_in[4];
    float* out = (float*)d_out;

    const int N = in_sizes[0];                  // 32768
    const int threads = 256;
    const int total = N * 4;                    // 4 threads per output point
    const int blocks = (total + threads - 1) / threads;   // 512

    umnn_pw<<<blocks, threads, 0, stream>>>(x, W1, b1, W2, b2, out, N);
}